// Round 15
// baseline (1117.386 us; speedup 1.0000x reference)
//
#include <hip/hip_runtime.h>

typedef __attribute__((ext_vector_type(8))) __bf16 bf16x8;
typedef __attribute__((ext_vector_type(4))) float f32x4;

#define MFMA16(a, b, c) __builtin_amdgcn_mfma_f32_16x16x32_bf16(a, b, c, 0, 0, 0)

#define T_SEQ 512
#define F_IN 32
#define H1 128
#define E2 64
#define ROWS 8          // batch rows per block (M-tile half full)

__device__ __forceinline__ float bf2f(ushort u) {
    union { uint i; float f; } v; v.i = ((uint)u) << 16; return v.f;
}
__device__ __forceinline__ ushort f2bf(float f) {
    union { float f; uint i; } v; v.f = f;
    uint r = v.i + 0x7fffu + ((v.i >> 16) & 1u);
    return (ushort)(r >> 16);
}
__device__ __forceinline__ float fast_sigmoid(float x) {
    float e = __expf(-x);
    return __builtin_amdgcn_rcpf(1.0f + e);
}
__device__ __forceinline__ float fast_tanh(float x) {
    float e = __expf(-2.0f * x);
    return 2.0f * __builtin_amdgcn_rcpf(1.0f + e) - 1.0f;
}
__device__ __forceinline__ bf16x8 load_w8(const float* p) {
    bf16x8 r;
#pragma unroll
    for (int j = 0; j < 8; ++j) r[j] = (__bf16)p[j];
    return r;
}
// LDS-only barrier: orders ds ops across waves WITHOUT draining vmcnt.
__device__ __forceinline__ void bar_lds() {
    __asm__ __volatile__("s_waitcnt lgkmcnt(0)\n\ts_barrier" ::: "memory");
}

// Fused 2-layer LSTM, two-phase, 64 blocks x 256 threads, 8 rows/block.
// r12 chassis (distributed LDS-gate epilogue beat r14's concentrated one).
// Changes vs r12: (1) 8 rows/block amortize the ~1500-cyc fixed per-step
// chain 4x (MFMA count is row-invariant); (2) recurrent states carried
// bf16-HI ONLY (h1-lo/h2-lo planes dropped: L1 48 MFMA/step, L2 24).
// Evidence for (2): phase-2 consumed hi-only h1 since r12, absmax never
// moved (9.77e-4 vs 3.93e-3 threshold). x keeps hi+lo.
__global__ __launch_bounds__(256, 1) void lstm_fused(
    const float* __restrict__ x,      // [512][512][32]
    const float* __restrict__ Wih1,   // [512][32]
    const float* __restrict__ Whh1,   // [512][128]
    const float* __restrict__ bih1,   // [512]
    const float* __restrict__ bhh1,   // [512]
    const float* __restrict__ Wih2,   // [256][128]
    const float* __restrict__ Whh2,   // [256][64]
    const float* __restrict__ bih2,   // [256]
    const float* __restrict__ bhh2,   // [256]
    ushort* __restrict__ h1ws,        // [512][512][128] bf16 hi (64 MiB d_ws)
    float* __restrict__ out)          // [512][64] fp32
{
    __shared__ ushort xs [16][72];    // x(t): cols 0..31 hi, 32..63 lo
    __shared__ ushort h1s[16][136];   // h1 hi only (cols 0..127)
    __shared__ ushort h2s[16][72];    // h2 hi only (cols 0..63)
    __shared__ float  g1r[ROWS][516]; // raw L1 gates
    __shared__ float  g2r[ROWS][260]; // raw L2 gates

    const int tid  = threadIdx.x;
    const int wave = tid >> 6;        // = gate type (i,f,g,o), both phases
    const int lane = tid & 63;
    const int l15  = lane & 15;
    const int quad = lane >> 4;
    const int r0   = blockIdx.x * ROWS;

    bf16x8 wf[40];
    float  bias[8];

    // ---- phase-1 weights: wave w owns L1 gate-type w, cols n=(w*8+j)*16+l15
#pragma unroll
    for (int j = 0; j < 8; ++j) {
        const int n = (wave * 8 + j) * 16 + l15;
#pragma unroll
        for (int kt = 0; kt < 4; ++kt)
            wf[j * 4 + kt] = load_w8(Whh1 + n * H1 + kt * 32 + quad * 8);
        wf[32 + j] = load_w8(Wih1 + n * F_IN + quad * 8);
        bias[j] = bih1[n] + bhh1[n];
    }

    // zero LDS state (rows >= ROWS stay zero forever -> zero A rows)
    for (int i = tid; i < 16 * 136; i += 256) ((ushort*)h1s)[i] = 0;
    for (int i = tid; i < 16 * 72;  i += 256) ((ushort*)h2s)[i] = 0;
    for (int i = tid; i < 16 * 72;  i += 256) ((ushort*)xs)[i]  = 0;
    __syncthreads();

    // ---------------- PHASE 1: layer 1, t = 0..511 ----------------
    {
        // epilogue: thread owns unit u = tid&127, rows rg*4..rg*4+3
        const int eu = tid & 127, rg = tid >> 7;
        float c1[4] = {0.0f, 0.0f, 0.0f, 0.0f};

        // x staging: thread owns (row = tid>>5, col = tid&31), 1 elem/step
        const int xrow = tid >> 5, xcol = tid & 31;
        const float* xptr = x + ((size_t)(r0 + xrow) * T_SEQ) * F_IN + xcol;
        float xreg = xptr[0];

        f32x4 acc[8];

#pragma unroll 1
        for (int t = 0; t < T_SEQ; ++t) {
            // stage x(t); prefetch x(t+1)
            {
                const ushort h = f2bf(xreg);
                xs[xrow][xcol]      = h;
                xs[xrow][32 + xcol] = f2bf(xreg - bf2f(h));
                if (t + 1 < T_SEQ) xreg = xptr[(t + 1) * F_IN];
            }
            bar_lds();   // B1: xs(t), h1s(t-1) visible

#pragma unroll
            for (int j = 0; j < 8; ++j)
                acc[j] = (f32x4){bias[j], bias[j], bias[j], bias[j]};
#pragma unroll
            for (int xt = 0; xt < 2; ++xt) {   // x hi, lo
                const bf16x8 ax = *(const bf16x8*)&xs[l15][xt * 32 + quad * 8];
#pragma unroll
                for (int j = 0; j < 8; ++j)
                    acc[j] = MFMA16(ax, wf[32 + j], acc[j]);
            }
#pragma unroll
            for (int kt = 0; kt < 4; ++kt) {   // h1 hi only
                const bf16x8 ah = *(const bf16x8*)&h1s[l15][kt * 32 + quad * 8];
#pragma unroll
                for (int j = 0; j < 8; ++j)
                    acc[j] = MFMA16(ah, wf[j * 4 + kt], acc[j]);
            }
            // gates -> LDS (C rows 0..7 live on quads 0..1)
            if (quad < 2) {
#pragma unroll
                for (int j = 0; j < 8; ++j)
#pragma unroll
                    for (int r = 0; r < 4; ++r)
                        g1r[quad * 4 + r][(wave * 8 + j) * 16 + l15] = acc[j][r];
            }
            bar_lds();   // B2: g1r ready; h1s/xs MFMA reads done

            // distributed epilogue: 4 updates/thread (rows rg*4+k, unit eu)
#pragma unroll
            for (int k = 0; k < 4; ++k) {
                const int row = rg * 4 + k;
                const float iv = fast_sigmoid(g1r[row][eu]);
                const float fv = fast_sigmoid(g1r[row][128 + eu]);
                const float gv = fast_tanh   (g1r[row][256 + eu]);
                const float ov = fast_sigmoid(g1r[row][384 + eu]);
                const float cn = fv * c1[k] + iv * gv;
                c1[k] = cn;
                const float h = ov * fast_tanh(cn);
                const ushort hi = f2bf(h);
                h1s[row][eu] = hi;
                h1ws[((size_t)(r0 + row) * T_SEQ + t) * H1 + eu] = hi;
            }
            // next-iter B1 covers h1s visibility
        }
    }

    __syncthreads();   // drain phase 1 (h1ws stores complete before readback)

    // ---- phase-2 weights: wave w owns L2 gate-type w, cols n=(w*4+j)*16+l15
#pragma unroll
    for (int j = 0; j < 4; ++j) {
        const int n = (wave * 4 + j) * 16 + l15;
#pragma unroll
        for (int kt = 0; kt < 4; ++kt)
            wf[j * 4 + kt] = load_w8(Wih2 + n * H1 + kt * 32 + quad * 8);
#pragma unroll
        for (int kt = 0; kt < 2; ++kt)
            wf[16 + j * 2 + kt] = load_w8(Whh2 + n * E2 + kt * 32 + quad * 8);
        bias[j] = bih2[n] + bhh2[n];
    }

    // ---------------- PHASE 2: layer 2, t = 0..511 ----------------
    {
        // epilogue: thread owns unit u = tid&63, rows rg2*2..rg2*2+1
        const int eu = tid & 63, rg2 = tid >> 6;
        float c2[2] = {0.0f, 0.0f};

        // h1 readback: thread owns uint-pair col p = tid&63 of rows
        // sr = (tid>>6)*2 + {0,1} -> 2 uints/step
        const int p = tid & 63, sr = (tid >> 6) * 2;
        const uint* uptrA = (const uint*)h1ws + ((size_t)(r0 + sr)     * T_SEQ) * 64 + p;
        const uint* uptrB = (const uint*)h1ws + ((size_t)(r0 + sr + 1) * T_SEQ) * 64 + p;
        uint uregA = uptrA[0], uregB = uptrB[0];

        f32x4 acc[4];

#pragma unroll 1
        for (int t = 0; t < T_SEQ; ++t) {
            // stage h1(t) into h1s rows 0..7 (hi, cols 0..127); prefetch t+1
            {
                *(uint*)&h1s[sr][2 * p]     = uregA;
                *(uint*)&h1s[sr + 1][2 * p] = uregB;
                if (t + 1 < T_SEQ) {
                    uregA = uptrA[(size_t)(t + 1) * 64];
                    uregB = uptrB[(size_t)(t + 1) * 64];
                }
            }
            bar_lds();   // B1: h1s(t), h2s(t-1) visible

#pragma unroll
            for (int j = 0; j < 4; ++j)
                acc[j] = (f32x4){bias[j], bias[j], bias[j], bias[j]};
#pragma unroll
            for (int kt = 0; kt < 4; ++kt) {   // h1 hi
                const bf16x8 a = *(const bf16x8*)&h1s[l15][kt * 32 + quad * 8];
#pragma unroll
                for (int j = 0; j < 4; ++j)
                    acc[j] = MFMA16(a, wf[j * 4 + kt], acc[j]);
            }
#pragma unroll
            for (int kt = 0; kt < 2; ++kt) {   // h2 hi
                const bf16x8 a = *(const bf16x8*)&h2s[l15][kt * 32 + quad * 8];
#pragma unroll
                for (int j = 0; j < 4; ++j)
                    acc[j] = MFMA16(a, wf[16 + j * 2 + kt], acc[j]);
            }
            if (quad < 2) {
#pragma unroll
                for (int j = 0; j < 4; ++j)
#pragma unroll
                    for (int r = 0; r < 4; ++r)
                        g2r[quad * 4 + r][(wave * 4 + j) * 16 + l15] = acc[j][r];
            }
            bar_lds();   // B2: g2r ready; h1s/h2s MFMA reads done

            // distributed epilogue: 2 updates/thread
#pragma unroll
            for (int k = 0; k < 2; ++k) {
                const int row = rg2 * 2 + k;
                const float iv = fast_sigmoid(g2r[row][eu]);
                const float fv = fast_sigmoid(g2r[row][64 + eu]);
                const float gv = fast_tanh   (g2r[row][128 + eu]);
                const float ov = fast_sigmoid(g2r[row][192 + eu]);
                const float cn = fv * c2[k] + iv * gv;
                c2[k] = cn;
                const float h = ov * fast_tanh(cn);
                h2s[row][eu] = f2bf(h);
                if (t == T_SEQ - 1)
                    out[(size_t)(r0 + row) * E2 + eu] = h;
            }
        }
    }
}

extern "C" void kernel_launch(void* const* d_in, const int* in_sizes, int n_in,
                              void* d_out, int out_size, void* d_ws, size_t ws_size,
                              hipStream_t stream) {
    lstm_fused<<<64, 256, 0, stream>>>(
        (const float*)d_in[0], (const float*)d_in[1], (const float*)d_in[2],
        (const float*)d_in[3], (const float*)d_in[4], (const float*)d_in[5],
        (const float*)d_in[6], (const float*)d_in[7], (const float*)d_in[8],
        (ushort*)d_ws, (float*)d_out);
}